// Round 1
// baseline (248.766 us; speedup 1.0000x reference)
//
#include <hip/hip_runtime.h>
#include <math.h>

// Problem constants (from reference)
constexpr int BB   = 2;
constexpr int CC   = 64;
constexpr int HH   = 128;
constexpr int WW   = 128;
constexpr int OO   = 64;
constexpr int HWSZ = HH * WW;    // 16384
constexpr int HOWO = 16384;      // Ho*Wo (stride1, pad1, 3x3 -> same size)
constexpr int OMC  = 27;         // offset/mask conv output channels

// ---------------------------------------------------------------------------
// Prep: transpose weights to [kk][c][o] so the hot loops read contiguous
// float4s of output-channel weights (wave-uniform addresses).
// wt_dcn: [9][64][64], wt_om: [9][64][32] (27 padded to 32 with zeros)
// ---------------------------------------------------------------------------
__global__ __launch_bounds__(256) void prep_transpose(
    const float* __restrict__ w_dcn, const float* __restrict__ w_om,
    float* __restrict__ wt_dcn, float* __restrict__ wt_om)
{
    int idx = blockIdx.x * 256 + threadIdx.x;
    if (idx < 9 * 64 * 64) {
        int o  = idx & 63;
        int c  = (idx >> 6) & 63;
        int kk = idx >> 12;
        wt_dcn[idx] = w_dcn[(o * CC + c) * 9 + kk];
    }
    if (idx < 9 * 64 * 32) {
        int o  = idx & 31;
        int c  = (idx >> 5) & 63;
        int kk = idx >> 11;
        wt_om[idx] = (o < OMC) ? w_om[(o * CC + c) * 9 + kk] : 0.f;
    }
}

// ---------------------------------------------------------------------------
// Kernel 1: 3x3 pad1 conv of input_offset -> 27 channels.
// Channels 0..17 -> offset output region of d_out; 18..26 -> sigmoid -> mask ws.
// Thread = one pixel, 16 output channels (blockIdx.y selects oc-half).
// ---------------------------------------------------------------------------
template<bool FAST>
__global__ __launch_bounds__(256) void conv_om_kernel(
    const float* __restrict__ x,      // input_offset [B][C][H][W]
    const float* __restrict__ w,      // w_om original [27][64][3][3] (slow path)
    const float* __restrict__ wt,     // [9][64][32] transposed (fast path)
    const float* __restrict__ bias,   // [27]
    float* __restrict__ off_out,      // d_out + outElems : [B][18][HoWo]
    float* __restrict__ mask_out)     // ws : [B][9][HoWo] (fast path)
{
    const int xid = blockIdx.x;                 // [0,128)
    const int b   = xid >> 6;
    const int p   = ((xid & 63) << 8) + threadIdx.x;
    const int ho  = p >> 7, wo = p & 127;
    const int oc0 = blockIdx.y << 4;            // 0 or 16

    float acc[16];
#pragma unroll
    for (int j = 0; j < 16; ++j) {
        const int oc = oc0 + j;
        acc[j] = (oc < OMC) ? bias[oc] : 0.f;
    }

    const float* xb = x + (size_t)b * CC * HWSZ;
    for (int c = 0; c < CC; ++c) {
        const float* xc = xb + c * HWSZ;
        float t[9];
#pragma unroll
        for (int kh = 0; kh < 3; ++kh) {
            const int ih = ho + kh - 1;
            const bool rv = (unsigned)ih < (unsigned)HH;
#pragma unroll
            for (int kw = 0; kw < 3; ++kw) {
                const int iw = wo + kw - 1;
                t[kh * 3 + kw] =
                    (rv && (unsigned)iw < (unsigned)WW) ? xc[ih * WW + iw] : 0.f;
            }
        }
        if (FAST) {
#pragma unroll
            for (int kk = 0; kk < 9; ++kk) {
                const float4* wr =
                    (const float4*)(wt + ((kk * 64 + c) << 5) + oc0);
                const float tv = t[kk];
#pragma unroll
                for (int q = 0; q < 4; ++q) {
                    const float4 wv = wr[q];
                    acc[q * 4 + 0] += tv * wv.x;
                    acc[q * 4 + 1] += tv * wv.y;
                    acc[q * 4 + 2] += tv * wv.z;
                    acc[q * 4 + 3] += tv * wv.w;
                }
            }
        } else {
#pragma unroll
            for (int j = 0; j < 16; ++j) {
                const int oc = oc0 + j;
                if (oc < OMC) {
                    const float* wj = w + (size_t)(oc * CC + c) * 9;
                    float s = 0.f;
#pragma unroll
                    for (int kk = 0; kk < 9; ++kk) s += t[kk] * wj[kk];
                    acc[j] += s;
                }
            }
        }
    }

#pragma unroll
    for (int j = 0; j < 16; ++j) {
        const int oc = oc0 + j;
        if (oc < 18) {
            off_out[(b * 18 + oc) * HOWO + p] = acc[j];
        } else if (oc < OMC) {
            if (FAST)
                mask_out[(b * 9 + (oc - 18)) * HOWO + p] =
                    1.f / (1.f + expf(-acc[j]));
        }
    }
}

// ---------------------------------------------------------------------------
// Kernel 2: modulated deformable conv.
// Thread = one pixel, 16 output channels (blockIdx.y in [0,4)).
// Bilinear sample v computed once per (kk,c), reused across 16 outputs.
// ---------------------------------------------------------------------------
template<bool FAST>
__global__ __launch_bounds__(256) void dcn_kernel(
    const float* __restrict__ xr,    // input_real
    const float* __restrict__ off,   // [B][18][HoWo] (written by kernel 1)
    const float* __restrict__ mask,  // [B][9][HoWo] (fast path)
    const float* __restrict__ wt,    // [9][64][64] transposed (fast path)
    const float* __restrict__ wd,    // w_dcn original [64][64][3][3]
    const float* __restrict__ bd,    // [64]
    float* __restrict__ out,         // [B][64][HoWo]
    const float* __restrict__ xo,    // input_offset (slow-path mask recompute)
    const float* __restrict__ wom,
    const float* __restrict__ bom)
{
    const int xid = blockIdx.x;
    const int b   = xid >> 6;
    const int p   = ((xid & 63) << 8) + threadIdx.x;
    const int ho  = p >> 7, wo = p & 127;
    const int o0  = blockIdx.y << 4;

    float acc[16];
#pragma unroll
    for (int j = 0; j < 16; ++j) acc[j] = bd[o0 + j];

    const float* xb = xr + (size_t)b * CC * HWSZ;

    for (int kk = 0; kk < 9; ++kk) {
        const float oy = off[(b * 18 + 2 * kk) * HOWO + p];
        const float ox = off[(b * 18 + 2 * kk + 1) * HOWO + p];
        float m;
        if (FAST) {
            m = mask[(b * 9 + kk) * HOWO + p];
        } else {
            float a = bom[18 + kk];
            const float* xob = xo + (size_t)b * CC * HWSZ;
            for (int c = 0; c < CC; ++c) {
                const float* xc2 = xob + c * HWSZ;
                const float* wj  = wom + (size_t)((18 + kk) * CC + c) * 9;
#pragma unroll
                for (int kh = 0; kh < 3; ++kh) {
                    const int ih = ho + kh - 1;
                    if ((unsigned)ih < (unsigned)HH) {
#pragma unroll
                        for (int kw = 0; kw < 3; ++kw) {
                            const int iw = wo + kw - 1;
                            if ((unsigned)iw < (unsigned)WW)
                                a += xc2[ih * WW + iw] * wj[kh * 3 + kw];
                        }
                    }
                }
            }
            m = 1.f / (1.f + expf(-a));
        }

        const int ky = kk / 3, kx = kk - ky * 3;
        const float yf = (float)(ho + ky - 1) + oy;
        const float xf = (float)(wo + kx - 1) + ox;
        const float y0 = floorf(yf), x0 = floorf(xf);
        const float ly = yf - y0, lx = xf - x0;
        const float hy = 1.f - ly, hx = 1.f - lx;
        const int iy0 = (int)y0, ix0 = (int)x0;
        const int iy1 = iy0 + 1, ix1 = ix0 + 1;
        const bool vy0 = (unsigned)iy0 < (unsigned)HH;
        const bool vy1 = (unsigned)iy1 < (unsigned)HH;
        const bool vx0 = (unsigned)ix0 < (unsigned)WW;
        const bool vx1 = (unsigned)ix1 < (unsigned)WW;
        const float w00 = (vy0 && vx0) ? hy * hx * m : 0.f;
        const float w01 = (vy0 && vx1) ? hy * lx * m : 0.f;
        const float w10 = (vy1 && vx0) ? ly * hx * m : 0.f;
        const float w11 = (vy1 && vx1) ? ly * lx * m : 0.f;
        const int cy0 = min(max(iy0, 0), HH - 1), cy1 = min(max(iy1, 0), HH - 1);
        const int cx0 = min(max(ix0, 0), WW - 1), cx1 = min(max(ix1, 0), WW - 1);
        const int i00 = cy0 * WW + cx0, i01 = cy0 * WW + cx1;
        const int i10 = cy1 * WW + cx0, i11 = cy1 * WW + cx1;

#pragma unroll 4
        for (int c = 0; c < CC; ++c) {
            const float* xc = xb + c * HWSZ;
            const float v = w00 * xc[i00] + w01 * xc[i01] +
                            w10 * xc[i10] + w11 * xc[i11];
            if (FAST) {
                const float4* wr =
                    (const float4*)(wt + ((kk * 64 + c) << 6) + o0);
#pragma unroll
                for (int q = 0; q < 4; ++q) {
                    const float4 wv = wr[q];
                    acc[q * 4 + 0] += v * wv.x;
                    acc[q * 4 + 1] += v * wv.y;
                    acc[q * 4 + 2] += v * wv.z;
                    acc[q * 4 + 3] += v * wv.w;
                }
            } else {
#pragma unroll
                for (int j = 0; j < 16; ++j)
                    acc[j] += v * wd[(size_t)((o0 + j) * CC + c) * 9 + kk];
            }
        }
    }

#pragma unroll
    for (int j = 0; j < 16; ++j)
        out[((size_t)b * OO + o0 + j) * HOWO + p] = acc[j];
}

// ---------------------------------------------------------------------------
extern "C" void kernel_launch(void* const* d_in, const int* in_sizes, int n_in,
                              void* d_out, int out_size, void* d_ws, size_t ws_size,
                              hipStream_t stream)
{
    const float* x_off  = (const float*)d_in[0];
    const float* x_real = (const float*)d_in[1];
    const float* w_om   = (const float*)d_in[2];
    const float* b_om   = (const float*)d_in[3];
    const float* w_dcn  = (const float*)d_in[4];
    const float* b_dcn  = (const float*)d_in[5];

    float* out = (float*)d_out;
    const int outElems = BB * OO * HOWO;          // 2,097,152
    float* off_out = out + outElems;              // [B][18][HoWo]

    const size_t maskFloats  = (size_t)BB * 9 * HOWO;   // 294,912
    const size_t wtDcnFloats = 9 * 64 * 64;             // 36,864
    const size_t wtOmFloats  = 9 * 64 * 32;             // 18,432
    const size_t need = (maskFloats + wtDcnFloats + wtOmFloats) * sizeof(float);

    if (ws_size >= need) {
        float* maskBuf = (float*)d_ws;
        float* wtDcn   = maskBuf + maskFloats;
        float* wtOm    = wtDcn + wtDcnFloats;
        hipLaunchKernelGGL(prep_transpose, dim3(144), dim3(256), 0, stream,
                           w_dcn, w_om, wtDcn, wtOm);
        hipLaunchKernelGGL((conv_om_kernel<true>), dim3(128, 2), dim3(256), 0,
                           stream, x_off, w_om, wtOm, b_om, off_out, maskBuf);
        hipLaunchKernelGGL((dcn_kernel<true>), dim3(128, 4), dim3(256), 0,
                           stream, x_real, off_out, maskBuf, wtDcn, w_dcn,
                           b_dcn, out, x_off, w_om, b_om);
    } else {
        hipLaunchKernelGGL((conv_om_kernel<false>), dim3(128, 2), dim3(256), 0,
                           stream, x_off, w_om, nullptr, b_om, off_out, nullptr);
        hipLaunchKernelGGL((dcn_kernel<false>), dim3(128, 4), dim3(256), 0,
                           stream, x_real, off_out, nullptr, nullptr, w_dcn,
                           b_dcn, out, x_off, w_om, b_om);
    }
}